// Round 1
// baseline (1014.412 us; speedup 1.0000x reference)
//
#include <hip/hip_runtime.h>

#define NN 50000
#define NE 800000
#define NIN 32
#define EIN 16
#define HID 128
#define NL 3
#define NG 256
#define TE 64

// ======================= CSR build (dst-sorted) =======================
__global__ void kZero(int* __restrict__ p, int n){
  int i = blockIdx.x*256 + threadIdx.x;
  if (i < n) p[i] = 0;
}

__global__ void kHist(const int* __restrict__ dst, int* __restrict__ cnt){
  int e = blockIdx.x*256 + threadIdx.x;
  if (e < NE) atomicAdd(&cnt[dst[e]], 1);
}

// single block, 1024 threads: exclusive scan of counts -> offs, cursor copy (in-place on cnt)
__global__ __launch_bounds__(1024) void kScan(int* __restrict__ cnt, int* __restrict__ offs){
  __shared__ int ps[1024];
  const int CH = (NN + 1023) / 1024;  // 49
  int t = threadIdx.x;
  int base = t * CH;
  int s = 0;
  for (int j = 0; j < CH; ++j){ int i = base + j; if (i < NN) s += cnt[i]; }
  ps[t] = s;
  __syncthreads();
  for (int off = 1; off < 1024; off <<= 1){
    int v = (t >= off) ? ps[t - off] : 0;
    __syncthreads();
    ps[t] += v;
    __syncthreads();
  }
  int run = (t == 0) ? 0 : ps[t-1];
  for (int j = 0; j < CH; ++j){
    int i = base + j;
    if (i < NN){ int c = cnt[i]; offs[i] = run; cnt[i] = run; run += c; }
  }
  if (t == 1023) offs[NN] = ps[1023];
}

__global__ void kScatter(const int* __restrict__ dst, int* __restrict__ curs, int* __restrict__ perm){
  int e = blockIdx.x*256 + threadIdx.x;
  if (e < NE){ int p = atomicAdd(&curs[dst[e]], 1); perm[p] = e; }
}

// ======================= node embed: h = x@W + b =======================
__global__ void kNodeInit(const float* __restrict__ x, const float* __restrict__ w,
                          const float* __restrict__ b, float* __restrict__ h){
  int gid = blockIdx.x*256 + threadIdx.x;
  if (gid >= NN*HID) return;
  int n = gid >> 7, c = gid & 127;
  const float* xr = x + n*NIN;
  float acc = b[c];
  #pragma unroll
  for (int k = 0; k < NIN; ++k) acc = fmaf(xr[k], w[k*HID + c], acc);
  h[gid] = acc;
}

// ======================= GINE aggregate (CSR, no atomics) =======================
// block = node, 128 threads = channels. z = (1+eps)*h + sum_{e: dst=n} relu(h[src]+ea@W+b)
__global__ __launch_bounds__(128) void kAgg(
    const float* __restrict__ h, const float* __restrict__ eattr,
    const int* __restrict__ esrc, const int* __restrict__ perm,
    const int* __restrict__ offs, const float* __restrict__ Wl,
    const float* __restrict__ bl, const float* __restrict__ epsArr, int layer,
    float* __restrict__ z, float* __restrict__ bnS, float* __restrict__ bnQ){
  int n = blockIdx.x;
  int c = threadIdx.x;
  if (n == 0){ bnS[c] = 0.f; bnQ[c] = 0.f; }   // zero stats for the following kMlp
  float w[EIN];
  #pragma unroll
  for (int k = 0; k < EIN; ++k) w[k] = Wl[k*HID + c];  // W column in registers
  float bias = bl[c];
  __shared__ float eas[16][EIN];
  __shared__ int pe[16];
  __shared__ int srcs[16];
  int s0 = offs[n], s1 = offs[n+1];
  float acc = 0.f;
  for (int j = s0; j < s1; j += 16){
    int cnt = min(16, s1 - j);
    __syncthreads();
    if (c < cnt){ int e = perm[j + c]; pe[c] = e; srcs[c] = esrc[e]; }
    __syncthreads();
    for (int t = c; t < cnt*EIN; t += HID)
      eas[t >> 4][t & 15] = eattr[pe[t >> 4]*EIN + (t & 15)];
    __syncthreads();
    #pragma unroll 4
    for (int i = 0; i < cnt; ++i){
      float hs = h[srcs[i]*HID + c];
      const float4* A = (const float4*)(&eas[i][0]);
      float4 a0 = A[0], a1 = A[1], a2 = A[2], a3 = A[3];
      float e0 = fmaf(a0.x, w[0], bias);
      float e1 = a0.y * w[1];
      e0 = fmaf(a0.z, w[2],  e0);  e1 = fmaf(a0.w, w[3],  e1);
      e0 = fmaf(a1.x, w[4],  e0);  e1 = fmaf(a1.y, w[5],  e1);
      e0 = fmaf(a1.z, w[6],  e0);  e1 = fmaf(a1.w, w[7],  e1);
      e0 = fmaf(a2.x, w[8],  e0);  e1 = fmaf(a2.y, w[9],  e1);
      e0 = fmaf(a2.z, w[10], e0);  e1 = fmaf(a2.w, w[11], e1);
      e0 = fmaf(a3.x, w[12], e0);  e1 = fmaf(a3.y, w[13], e1);
      e0 = fmaf(a3.z, w[14], e0);  e1 = fmaf(a3.w, w[15], e1);
      acc += fmaxf(hs + e0 + e1, 0.f);
    }
  }
  float ep = epsArr[layer];
  int gi = n*HID + c;
  z[gi] = (1.f + ep)*h[gi] + acc;
}

// ======================= fused MLP: z2 = relu(z@W1+b1)@W2+b2, + BN partials =======================
#define MLP_TM 128
#define AST 132   // aT row stride (pad: bank-spread + 16B aligned)
#define WST 140   // Ws row stride after swizzle
__device__ __forceinline__ int swzW(int cidx){ return cidx + ((cidx >> 5) << 2); }

__global__ __launch_bounds__(256, 1) void kMlp(
    const float* __restrict__ z, float* __restrict__ z2,
    const float* __restrict__ W1, const float* __restrict__ b1,
    const float* __restrict__ W2, const float* __restrict__ b2,
    float* __restrict__ bnS, float* __restrict__ bnQ){
  __shared__ float Ws[128*WST];      // 70 KB
  __shared__ float aT[128*AST];      // 66 KB (A-tile transposed, reused as t-tile)
  __shared__ float red[256];         // BN partial sums/sumsq
  int tid = threadIdx.x;
  int rbase = blockIdx.x * MLP_TM;

  for (int i = tid; i < 128*128; i += 256){
    int k = i >> 7, cc = i & 127;
    Ws[k*WST + swzW(cc)] = W1[i];
  }
  for (int i = tid; i < MLP_TM*128; i += 256){
    int rr = i >> 7, k = i & 127;
    int r = rbase + rr;
    aT[k*AST + rr] = (r < NN) ? z[r*HID + k] : 0.f;
  }
  __syncthreads();

  int tr = tid >> 4, tc = tid & 15;
  int r0 = tr*8, c0 = tc*8;
  int sw0 = swzW(c0), sw4 = swzW(c0 + 4);

  float acc[8][8];
  #pragma unroll
  for (int i = 0; i < 8; ++i)
    #pragma unroll
    for (int j = 0; j < 8; ++j) acc[i][j] = 0.f;

  #pragma unroll 8
  for (int k = 0; k < 128; ++k){
    float4 a0 = *(const float4*)&aT[k*AST + r0];
    float4 a1 = *(const float4*)&aT[k*AST + r0 + 4];
    float4 w0 = *(const float4*)&Ws[k*WST + sw0];
    float4 w1 = *(const float4*)&Ws[k*WST + sw4];
    float av[8] = {a0.x,a0.y,a0.z,a0.w,a1.x,a1.y,a1.z,a1.w};
    float wv[8] = {w0.x,w0.y,w0.z,w0.w,w1.x,w1.y,w1.z,w1.w};
    #pragma unroll
    for (int i = 0; i < 8; ++i)
      #pragma unroll
      for (int j = 0; j < 8; ++j) acc[i][j] = fmaf(av[i], wv[j], acc[i][j]);
  }

  __syncthreads();  // all aT/Ws reads of GEMM1 done
  // t = relu(acc + b1), written transposed into aT (t-tile); stage W2 into Ws
  {
    float bv[8];
    #pragma unroll
    for (int j = 0; j < 8; ++j) bv[j] = b1[c0 + j];
    #pragma unroll
    for (int j = 0; j < 8; ++j){
      int cc = c0 + j;
      float4 v0 = make_float4(fmaxf(acc[0][j]+bv[j],0.f), fmaxf(acc[1][j]+bv[j],0.f),
                              fmaxf(acc[2][j]+bv[j],0.f), fmaxf(acc[3][j]+bv[j],0.f));
      float4 v1 = make_float4(fmaxf(acc[4][j]+bv[j],0.f), fmaxf(acc[5][j]+bv[j],0.f),
                              fmaxf(acc[6][j]+bv[j],0.f), fmaxf(acc[7][j]+bv[j],0.f));
      *(float4*)&aT[cc*AST + r0]     = v0;
      *(float4*)&aT[cc*AST + r0 + 4] = v1;
    }
  }
  for (int i = tid; i < 128*128; i += 256){
    int k = i >> 7, cc = i & 127;
    Ws[k*WST + swzW(cc)] = W2[i];
  }
  #pragma unroll
  for (int i = 0; i < 8; ++i)
    #pragma unroll
    for (int j = 0; j < 8; ++j) acc[i][j] = 0.f;
  __syncthreads();

  #pragma unroll 8
  for (int k = 0; k < 128; ++k){
    float4 a0 = *(const float4*)&aT[k*AST + r0];
    float4 a1 = *(const float4*)&aT[k*AST + r0 + 4];
    float4 w0 = *(const float4*)&Ws[k*WST + sw0];
    float4 w1 = *(const float4*)&Ws[k*WST + sw4];
    float av[8] = {a0.x,a0.y,a0.z,a0.w,a1.x,a1.y,a1.z,a1.w};
    float wv[8] = {w0.x,w0.y,w0.z,w0.w,w1.x,w1.y,w1.z,w1.w};
    #pragma unroll
    for (int i = 0; i < 8; ++i)
      #pragma unroll
      for (int j = 0; j < 8; ++j) acc[i][j] = fmaf(av[i], wv[j], acc[i][j]);
  }

  // epilogue: z2 = acc + b2, BN partial stats
  float b2v[8];
  #pragma unroll
  for (int j = 0; j < 8; ++j) b2v[j] = b2[c0 + j];
  float ps[8], pq[8];
  #pragma unroll
  for (int j = 0; j < 8; ++j){ ps[j] = 0.f; pq[j] = 0.f; }
  #pragma unroll
  for (int i = 0; i < 8; ++i){
    int r = rbase + r0 + i;
    if (r < NN){
      float v[8];
      #pragma unroll
      for (int j = 0; j < 8; ++j){ v[j] = acc[i][j] + b2v[j]; ps[j] += v[j]; pq[j] += v[j]*v[j]; }
      *(float4*)&z2[r*HID + c0]     = make_float4(v[0],v[1],v[2],v[3]);
      *(float4*)&z2[r*HID + c0 + 4] = make_float4(v[4],v[5],v[6],v[7]);
    }
  }
  red[tid] = 0.f;
  __syncthreads();
  #pragma unroll
  for (int j = 0; j < 8; ++j){
    atomicAdd(&red[c0 + j], ps[j]);
    atomicAdd(&red[128 + ((c0 + j) & 127)], pq[j]);
  }
  __syncthreads();
  if (tid < 128){
    atomicAdd(&bnS[tid], red[tid]);
    atomicAdd(&bnQ[tid], red[128 + tid]);
  }
}

// ======================= BN apply + ReLU -> h =======================
__global__ void kBn(const float* __restrict__ z2, const float* __restrict__ bnS,
                    const float* __restrict__ bnQ, const float* __restrict__ gamma,
                    const float* __restrict__ beta, float* __restrict__ h){
  int gid = blockIdx.x*256 + threadIdx.x;
  if (gid >= NN*HID) return;
  int c = gid & 127;
  float mean = bnS[c] * (1.f/NN);
  float var  = bnQ[c] * (1.f/NN) - mean*mean;
  float inv  = rsqrtf(var + 1e-5f);
  float v = (z2[gid] - mean)*inv*gamma[c] + beta[c];
  h[gid] = fmaxf(v, 0.f);
}

// ======================= pool (sorted batch_ids, binary search) =======================
__global__ __launch_bounds__(192) void kPool(const float* __restrict__ h, const int* __restrict__ bid,
                      const int* __restrict__ tidx, const float* __restrict__ temb,
                      float* __restrict__ g){
  int b = blockIdx.x, t = threadIdx.x;
  int lo = 0, hi = NN;
  while (lo < hi){ int m = (lo + hi) >> 1; if (bid[m] < b) lo = m + 1; else hi = m; }
  int s = lo;
  lo = 0; hi = NN;
  while (lo < hi){ int m = (lo + hi) >> 1; if (bid[m] < b + 1) lo = m + 1; else hi = m; }
  int e = lo;
  if (t < HID){
    float acc = 0.f;
    for (int n = s; n < e; ++n) acc += h[n*HID + t];
    g[b*192 + t] = acc;
  } else {
    int j = t - HID;
    g[b*192 + HID + j] = temb[tidx[b]*TE + j];
  }
}

// ======================= head MLP =======================
__global__ __launch_bounds__(128) void kHead(const float* __restrict__ g,
    const float* __restrict__ w1, const float* __restrict__ b1,
    const float* __restrict__ w2, const float* __restrict__ b2,
    const float* __restrict__ w3, const float* __restrict__ b3,
    float* __restrict__ out){
  __shared__ float gv[192];
  __shared__ float t1[128];
  __shared__ float t2[64];
  int b = blockIdx.x, t = threadIdx.x;
  gv[t] = g[b*192 + t];
  if (t < 64) gv[128 + t] = g[b*192 + 128 + t];
  __syncthreads();
  float acc = b1[t];
  for (int k = 0; k < 192; ++k) acc = fmaf(gv[k], w1[k*HID + t], acc);
  t1[t] = fmaxf(acc, 0.f);
  __syncthreads();
  if (t < 64){
    float a2 = b2[t];
    for (int k = 0; k < 128; ++k) a2 = fmaf(t1[k], w2[k*64 + t], a2);
    t2[t] = fmaxf(a2, 0.f);
  }
  __syncthreads();
  if (t == 0){
    float s = b3[0];
    for (int k = 0; k < 64; ++k) s = fmaf(t2[k], w3[k], s);
    out[b] = s;
  }
}

// ======================= launch =======================
extern "C" void kernel_launch(void* const* d_in, const int* in_sizes, int n_in,
                              void* d_out, int out_size, void* d_ws, size_t ws_size,
                              hipStream_t stream){
  const float* x     = (const float*)d_in[0];
  const int*   ei    = (const int*)  d_in[1];
  const float* eattr = (const float*)d_in[2];
  const int*   bids  = (const int*)  d_in[3];
  const int*   tgt   = (const int*)  d_in[4];
  const float* nw    = (const float*)d_in[5];
  const float* nb    = (const float*)d_in[6];
  const float* eps   = (const float*)d_in[7];
  const float* ew    = (const float*)d_in[8];
  const float* eb    = (const float*)d_in[9];
  const float* w1    = (const float*)d_in[10];
  const float* bb1   = (const float*)d_in[11];
  const float* w2    = (const float*)d_in[12];
  const float* bb2   = (const float*)d_in[13];
  const float* gam   = (const float*)d_in[14];
  const float* bet   = (const float*)d_in[15];
  const float* temb  = (const float*)d_in[16];
  const float* h1w   = (const float*)d_in[17];
  const float* h1b   = (const float*)d_in[18];
  const float* h2w   = (const float*)d_in[19];
  const float* h2b   = (const float*)d_in[20];
  const float* h3w   = (const float*)d_in[21];
  const float* h3b   = (const float*)d_in[22];
  float* out = (float*)d_out;

  float* ws  = (float*)d_ws;
  float* h   = ws;                  // NN*HID
  float* z   = h  + (size_t)NN*HID; // NN*HID
  float* z2  = z  + (size_t)NN*HID; // NN*HID
  float* g   = z2 + (size_t)NN*HID; // NG*192
  float* bnS = g  + (size_t)NG*192; // 128
  float* bnQ = bnS + HID;           // 128
  int* offs  = (int*)(bnQ + HID);   // NN+1
  int* curs  = offs + NN + 1;       // NN
  int* perm  = curs + NN;           // NE

  const int* esrc = ei;
  const int* edst = ei + NE;

  kZero   <<<(NN + 255)/256, 256, 0, stream>>>(curs, NN);
  kHist   <<<(NE + 255)/256, 256, 0, stream>>>(edst, curs);
  kScan   <<<1, 1024, 0, stream>>>(curs, offs);
  kScatter<<<(NE + 255)/256, 256, 0, stream>>>(edst, curs, perm);
  kNodeInit<<<(NN*HID + 255)/256, 256, 0, stream>>>(x, nw, nb, h);

  for (int l = 0; l < NL; ++l){
    kAgg<<<NN, 128, 0, stream>>>(h, eattr, esrc, perm, offs,
                                 ew + (size_t)l*EIN*HID, eb + (size_t)l*HID, eps, l,
                                 z, bnS, bnQ);
    kMlp<<<(NN + MLP_TM - 1)/MLP_TM, 256, 0, stream>>>(z, z2,
                                 w1 + (size_t)l*HID*HID, bb1 + (size_t)l*HID,
                                 w2 + (size_t)l*HID*HID, bb2 + (size_t)l*HID,
                                 bnS, bnQ);
    kBn<<<(NN*HID + 255)/256, 256, 0, stream>>>(z2, bnS, bnQ,
                                 gam + (size_t)l*HID, bet + (size_t)l*HID, h);
  }

  kPool<<<NG, 192, 0, stream>>>(h, bids, tgt, temb, g);
  kHead<<<NG, 128, 0, stream>>>(g, h1w, h1b, h2w, h2b, h3w, h3b, out);
}

// Round 2
// 888.200 us; speedup vs baseline: 1.1421x; 1.1421x over previous
//
#include <hip/hip_runtime.h>

#define NN 50000
#define NE 800000
#define NIN 32
#define EIN 16
#define HID 128
#define NL 3
#define NG 256
#define TE 64
#define BM 64   // kMlp row tile

typedef unsigned short ushort_t;
typedef __attribute__((ext_vector_type(8))) short short8;
typedef __attribute__((ext_vector_type(4))) float f32x4;

__device__ __forceinline__ ushort_t f2bf(float x){
  unsigned u = __float_as_uint(x);
  unsigned r = (u + 0x7fffu + ((u >> 16) & 1u)) >> 16;
  return (ushort_t)r;
}
__device__ __forceinline__ float bf2f(ushort_t v){
  return __uint_as_float(((unsigned)v) << 16);
}

typedef const __attribute__((address_space(1))) unsigned gas_t;
typedef __attribute__((address_space(3))) unsigned las_t;
__device__ __forceinline__ void stage16(const void* g, void* l){
  __builtin_amdgcn_global_load_lds((gas_t*)g, (las_t*)l, 16, 0, 0);
}

// ======================= CSR build (dst-sorted) =======================
__global__ void kZero(int* __restrict__ p, int n){
  int i = blockIdx.x*256 + threadIdx.x;
  if (i < n) p[i] = 0;
}

__global__ void kHist(const int* __restrict__ dst, int* __restrict__ cnt){
  int e = blockIdx.x*256 + threadIdx.x;
  if (e < NE) atomicAdd(&cnt[dst[e]], 1);
}

__global__ __launch_bounds__(1024) void kScan(int* __restrict__ cnt, int* __restrict__ offs){
  __shared__ int ps[1024];
  const int CH = (NN + 1023) / 1024;  // 49
  int t = threadIdx.x;
  int base = t * CH;
  int s = 0;
  for (int j = 0; j < CH; ++j){ int i = base + j; if (i < NN) s += cnt[i]; }
  ps[t] = s;
  __syncthreads();
  for (int off = 1; off < 1024; off <<= 1){
    int v = (t >= off) ? ps[t - off] : 0;
    __syncthreads();
    ps[t] += v;
    __syncthreads();
  }
  int run = (t == 0) ? 0 : ps[t-1];
  for (int j = 0; j < CH; ++j){
    int i = base + j;
    if (i < NN){ int c = cnt[i]; offs[i] = run; cnt[i] = run; run += c; }
  }
  if (t == 1023) offs[NN] = ps[1023];
}

__global__ void kScatter(const int* __restrict__ dst, int* __restrict__ curs, int* __restrict__ perm){
  int e = blockIdx.x*256 + threadIdx.x;
  if (e < NE){ int p = atomicAdd(&curs[dst[e]], 1); perm[p] = e; }
}

// ======================= W -> bf16, transposed + pre-swizzled; zero zb tail =======================
// wtb[mat][n*128 + (k ^ ((n&7)<<3))] = bf16(W[mat][k][n]),  mat 0..2 = W1 layers, 3..5 = W2
__global__ void kConvW(const float* __restrict__ w1, const float* __restrict__ w2,
                       ushort_t* __restrict__ wtb, ushort_t* __restrict__ zb){
  int gid = blockIdx.x*256 + threadIdx.x;
  if (gid < 6*16384){
    int mat = gid >> 14, idx = gid & 16383;
    int k = idx >> 7, n = idx & 127;
    const float* src = (mat < 3) ? (w1 + (size_t)mat*16384) : (w2 + (size_t)(mat-3)*16384);
    wtb[(size_t)mat*16384 + n*128 + (k ^ ((n&7)<<3))] = f2bf(src[idx]);
  } else {
    int t = gid - 6*16384;
    if (t < 48*128) zb[(size_t)NN*HID + t] = 0;  // zero pad rows 50000..50047
  }
}

// ======================= node embed: h = x@W + b =======================
__global__ void kNodeInit(const float* __restrict__ x, const float* __restrict__ w,
                          const float* __restrict__ b, float* __restrict__ h,
                          ushort_t* __restrict__ hbf){
  int gid = blockIdx.x*256 + threadIdx.x;
  if (gid >= NN*HID) return;
  int n = gid >> 7, c = gid & 127;
  const float* xr = x + n*NIN;
  float acc = b[c];
  #pragma unroll
  for (int k = 0; k < NIN; ++k) acc = fmaf(xr[k], w[k*HID + c], acc);
  h[gid] = acc;
  hbf[gid] = f2bf(acc);
}

// ======================= GINE aggregate (CSR, no atomics) =======================
// block = node, 128 threads = channels. zb = preswizzled bf16 of (1+eps)*h + sum relu(h[src]+ea@W+b)
__global__ __launch_bounds__(128) void kAgg(
    const float* __restrict__ h, const ushort_t* __restrict__ hbf,
    const float* __restrict__ eattr,
    const int* __restrict__ esrc, const int* __restrict__ perm,
    const int* __restrict__ offs, const float* __restrict__ Wl,
    const float* __restrict__ bl, const float* __restrict__ epsArr, int layer,
    ushort_t* __restrict__ zb, float* __restrict__ bnS, float* __restrict__ bnQ){
  int n = blockIdx.x;
  int c = threadIdx.x;
  if (n == 0){ bnS[c] = 0.f; bnQ[c] = 0.f; }   // zero stats for the following kMlp
  float w[EIN];
  #pragma unroll
  for (int k = 0; k < EIN; ++k) w[k] = Wl[k*HID + c];  // W column in registers
  float bias = bl[c];
  __shared__ float eas[16][EIN];
  __shared__ int pe[16];
  __shared__ int srcs[16];
  int s0 = offs[n], s1 = offs[n+1];
  float acc = 0.f;
  for (int j = s0; j < s1; j += 16){
    int cnt = min(16, s1 - j);
    __syncthreads();
    if (c < cnt){ int e = perm[j + c]; pe[c] = e; srcs[c] = esrc[e]; }
    __syncthreads();
    for (int t = c; t < cnt*EIN; t += HID)
      eas[t >> 4][t & 15] = eattr[pe[t >> 4]*EIN + (t & 15)];
    __syncthreads();
    #pragma unroll 8
    for (int i = 0; i < cnt; ++i){
      float hs = bf2f(hbf[(size_t)srcs[i]*HID + c]);
      const float4* A = (const float4*)(&eas[i][0]);
      float4 a0 = A[0], a1 = A[1], a2 = A[2], a3 = A[3];
      float e0 = fmaf(a0.x, w[0], bias);
      float e1 = a0.y * w[1];
      e0 = fmaf(a0.z, w[2],  e0);  e1 = fmaf(a0.w, w[3],  e1);
      e0 = fmaf(a1.x, w[4],  e0);  e1 = fmaf(a1.y, w[5],  e1);
      e0 = fmaf(a1.z, w[6],  e0);  e1 = fmaf(a1.w, w[7],  e1);
      e0 = fmaf(a2.x, w[8],  e0);  e1 = fmaf(a2.y, w[9],  e1);
      e0 = fmaf(a2.z, w[10], e0);  e1 = fmaf(a2.w, w[11], e1);
      e0 = fmaf(a3.x, w[12], e0);  e1 = fmaf(a3.y, w[13], e1);
      e0 = fmaf(a3.z, w[14], e0);  e1 = fmaf(a3.w, w[15], e1);
      acc += fmaxf(hs + e0 + e1, 0.f);
    }
  }
  float ep = epsArr[layer];
  float zv = (1.f + ep)*h[(size_t)n*HID + c] + acc;
  zb[(size_t)n*HID + (c ^ ((n&7)<<3))] = f2bf(zv);
}

// ======================= fused MLP via MFMA: z2 = relu(zb@W1+b1)@W2+b2, + BN partials =======================
// 256 threads = 4 waves (2x2), BM=64 rows, full N=128, K=128.
// LDS: As [64][128] bf16 swizzled (halfword idx = m*128 + (k ^ ((m&7)<<3))), Bs [128][128] bf16 (Wt, same swizzle).
__global__ __launch_bounds__(256, 1) void kMlp(
    const ushort_t* __restrict__ zb, float* __restrict__ z2,
    const ushort_t* __restrict__ w1t, const float* __restrict__ b1,
    const ushort_t* __restrict__ w2t, const float* __restrict__ b2,
    float* __restrict__ bnS, float* __restrict__ bnQ){
  __shared__ __align__(16) ushort_t As[BM*128];     // 16 KB
  __shared__ __align__(16) ushort_t Bs[128*128];    // 32 KB
  __shared__ float red[256];
  int tid  = threadIdx.x;
  int lane = tid & 63;
  int w    = tid >> 6;
  int ln   = tid & 15;
  int q    = (tid >> 4) & 3;
  int rbase = blockIdx.x * BM;
  int m0 = (w >> 1) * 32;    // wave row base within tile
  int wc = (w & 1) * 64;     // wave col base

  // stage A (16KB) + W1 (32KB) via global_load_lds (sources are pre-swizzled)
  const char* gA = (const char*)(zb + (size_t)rbase * HID);
  #pragma unroll
  for (int it = 0; it < 4; ++it)
    stage16(gA + (w*4096 + it*1024 + lane*16), (char*)As + (w*4096 + it*1024));
  const char* gB1 = (const char*)w1t;
  #pragma unroll
  for (int it = 0; it < 8; ++it)
    stage16(gB1 + (w*8192 + it*1024 + lane*16), (char*)Bs + (w*8192 + it*1024));
  __syncthreads();

  f32x4 acc[2][4];
  #pragma unroll
  for (int i = 0; i < 2; ++i)
    #pragma unroll
    for (int j = 0; j < 4; ++j) acc[i][j] = (f32x4)0.f;

  // GEMM1: acc = zb_tile @ W1
  #pragma unroll
  for (int kk = 0; kk < 4; ++kk){
    int kb = kk*32 + q*8;
    short8 af[2], bf[4];
    #pragma unroll
    for (int i = 0; i < 2; ++i){
      int m = m0 + 16*i + ln;
      af[i] = *(const short8*)&As[m*128 + (kb ^ ((m&7)<<3))];
    }
    #pragma unroll
    for (int j = 0; j < 4; ++j){
      int n = wc + 16*j + ln;
      bf[j] = *(const short8*)&Bs[n*128 + (kb ^ ((n&7)<<3))];
    }
    #pragma unroll
    for (int i = 0; i < 2; ++i)
      #pragma unroll
      for (int j = 0; j < 4; ++j)
        acc[i][j] = __builtin_amdgcn_mfma_f32_16x16x32_bf16(af[i], bf[j], acc[i][j], 0, 0, 0);
  }
  __syncthreads();   // GEMM1 LDS reads complete

  // prefetch W2 into Bs; write t = relu(acc+b1) as bf16 into As (swizzled)
  const char* gB2 = (const char*)w2t;
  #pragma unroll
  for (int it = 0; it < 8; ++it)
    stage16(gB2 + (w*8192 + it*1024 + lane*16), (char*)Bs + (w*8192 + it*1024));
  {
    float b1v[4];
    #pragma unroll
    for (int j = 0; j < 4; ++j) b1v[j] = b1[wc + 16*j + ln];
    #pragma unroll
    for (int i = 0; i < 2; ++i){
      #pragma unroll
      for (int j = 0; j < 4; ++j){
        int kc = wc + 16*j + ln;
        #pragma unroll
        for (int r = 0; r < 4; ++r){
          int m = m0 + 16*i + 4*q + r;
          As[m*128 + (kc ^ ((m&7)<<3))] = f2bf(fmaxf(acc[i][j][r] + b1v[j], 0.f));
        }
      }
    }
  }
  #pragma unroll
  for (int i = 0; i < 2; ++i)
    #pragma unroll
    for (int j = 0; j < 4; ++j) acc[i][j] = (f32x4)0.f;
  __syncthreads();   // t in As, W2 in Bs

  // GEMM2: acc = t @ W2
  #pragma unroll
  for (int kk = 0; kk < 4; ++kk){
    int kb = kk*32 + q*8;
    short8 af[2], bf[4];
    #pragma unroll
    for (int i = 0; i < 2; ++i){
      int m = m0 + 16*i + ln;
      af[i] = *(const short8*)&As[m*128 + (kb ^ ((m&7)<<3))];
    }
    #pragma unroll
    for (int j = 0; j < 4; ++j){
      int n = wc + 16*j + ln;
      bf[j] = *(const short8*)&Bs[n*128 + (kb ^ ((n&7)<<3))];
    }
    #pragma unroll
    for (int i = 0; i < 2; ++i)
      #pragma unroll
      for (int j = 0; j < 4; ++j)
        acc[i][j] = __builtin_amdgcn_mfma_f32_16x16x32_bf16(af[i], bf[j], acc[i][j], 0, 0, 0);
  }

  // epilogue: z2 = acc + b2 (fp32), BN partial stats
  float b2v[4];
  #pragma unroll
  for (int j = 0; j < 4; ++j) b2v[j] = b2[wc + 16*j + ln];
  float ps[4], pq[4];
  #pragma unroll
  for (int j = 0; j < 4; ++j){ ps[j] = 0.f; pq[j] = 0.f; }
  #pragma unroll
  for (int i = 0; i < 2; ++i){
    #pragma unroll
    for (int r = 0; r < 4; ++r){
      int rg = rbase + m0 + 16*i + 4*q + r;
      if (rg < NN){
        #pragma unroll
        for (int j = 0; j < 4; ++j){
          float v = acc[i][j][r] + b2v[j];
          z2[(size_t)rg*HID + wc + 16*j + ln] = v;
          ps[j] += v; pq[j] += v*v;
        }
      }
    }
  }
  red[tid] = 0.f;
  if (tid < 128) red[128 + tid] = 0.f;   // red[0..127]=sum, red[128..255]=sumsq
  __syncthreads();
  #pragma unroll
  for (int j = 0; j < 4; ++j){
    int c = wc + 16*j + ln;
    atomicAdd(&red[c], ps[j]);
    atomicAdd(&red[128 + c], pq[j]);
  }
  __syncthreads();
  if (tid < 128){
    atomicAdd(&bnS[tid], red[tid]);
    atomicAdd(&bnQ[tid], red[128 + tid]);
  }
}

// ======================= BN apply + ReLU -> h (fp32) and hbf (bf16) =======================
__global__ void kBn(const float* __restrict__ z2, const float* __restrict__ bnS,
                    const float* __restrict__ bnQ, const float* __restrict__ gamma,
                    const float* __restrict__ beta, float* __restrict__ h,
                    ushort_t* __restrict__ hbf){
  int gid = blockIdx.x*256 + threadIdx.x;
  if (gid >= NN*HID) return;
  int c = gid & 127;
  float mean = bnS[c] * (1.f/NN);
  float var  = bnQ[c] * (1.f/NN) - mean*mean;
  float inv  = rsqrtf(var + 1e-5f);
  float v = (z2[gid] - mean)*inv*gamma[c] + beta[c];
  v = fmaxf(v, 0.f);
  h[gid] = v;
  hbf[gid] = f2bf(v);
}

// ======================= pool (sorted batch_ids, binary search) =======================
__global__ __launch_bounds__(192) void kPool(const float* __restrict__ h, const int* __restrict__ bid,
                      const int* __restrict__ tidx, const float* __restrict__ temb,
                      float* __restrict__ g){
  int b = blockIdx.x, t = threadIdx.x;
  int lo = 0, hi = NN;
  while (lo < hi){ int m = (lo + hi) >> 1; if (bid[m] < b) lo = m + 1; else hi = m; }
  int s = lo;
  lo = 0; hi = NN;
  while (lo < hi){ int m = (lo + hi) >> 1; if (bid[m] < b + 1) lo = m + 1; else hi = m; }
  int e = lo;
  if (t < HID){
    float acc = 0.f;
    for (int n = s; n < e; ++n) acc += h[n*HID + t];
    g[b*192 + t] = acc;
  } else {
    int j = t - HID;
    g[b*192 + HID + j] = temb[tidx[b]*TE + j];
  }
}

// ======================= head MLP =======================
__global__ __launch_bounds__(128) void kHead(const float* __restrict__ g,
    const float* __restrict__ w1, const float* __restrict__ b1,
    const float* __restrict__ w2, const float* __restrict__ b2,
    const float* __restrict__ w3, const float* __restrict__ b3,
    float* __restrict__ out){
  __shared__ float gv[192];
  __shared__ float t1[128];
  __shared__ float t2[64];
  int b = blockIdx.x, t = threadIdx.x;
  gv[t] = g[b*192 + t];
  if (t < 64) gv[128 + t] = g[b*192 + 128 + t];
  __syncthreads();
  float acc = b1[t];
  for (int k = 0; k < 192; ++k) acc = fmaf(gv[k], w1[k*HID + t], acc);
  t1[t] = fmaxf(acc, 0.f);
  __syncthreads();
  if (t < 64){
    float a2 = b2[t];
    for (int k = 0; k < 128; ++k) a2 = fmaf(t1[k], w2[k*64 + t], a2);
    t2[t] = fmaxf(a2, 0.f);
  }
  __syncthreads();
  if (t == 0){
    float s = b3[0];
    for (int k = 0; k < 64; ++k) s = fmaf(t2[k], w3[k], s);
    out[b] = s;
  }
}

// ======================= launch =======================
extern "C" void kernel_launch(void* const* d_in, const int* in_sizes, int n_in,
                              void* d_out, int out_size, void* d_ws, size_t ws_size,
                              hipStream_t stream){
  const float* x     = (const float*)d_in[0];
  const int*   ei    = (const int*)  d_in[1];
  const float* eattr = (const float*)d_in[2];
  const int*   bids  = (const int*)  d_in[3];
  const int*   tgt   = (const int*)  d_in[4];
  const float* nw    = (const float*)d_in[5];
  const float* nb    = (const float*)d_in[6];
  const float* eps   = (const float*)d_in[7];
  const float* ew    = (const float*)d_in[8];
  const float* eb    = (const float*)d_in[9];
  const float* w1    = (const float*)d_in[10];
  const float* bb1   = (const float*)d_in[11];
  const float* w2    = (const float*)d_in[12];
  const float* bb2   = (const float*)d_in[13];
  const float* gam   = (const float*)d_in[14];
  const float* bet   = (const float*)d_in[15];
  const float* temb  = (const float*)d_in[16];
  const float* h1w   = (const float*)d_in[17];
  const float* h1b   = (const float*)d_in[18];
  const float* h2w   = (const float*)d_in[19];
  const float* h2b   = (const float*)d_in[20];
  const float* h3w   = (const float*)d_in[21];
  const float* h3b   = (const float*)d_in[22];
  float* out = (float*)d_out;

  // bf16 buffers first (16B-aligned sizes), fp32/int after
  ushort_t* zb  = (ushort_t*)d_ws;                      // 50048*128
  ushort_t* wtb = zb + (size_t)(NN + 48)*HID;           // 6*16384
  ushort_t* hbf = wtb + (size_t)6*16384;                // NN*128
  float* h   = (float*)(hbf + (size_t)NN*HID);          // NN*128
  float* z2  = h  + (size_t)NN*HID;                     // NN*128
  float* g   = z2 + (size_t)NN*HID;                     // NG*192
  float* bnS = g  + (size_t)NG*192;                     // 128
  float* bnQ = bnS + HID;                               // 128
  int* offs  = (int*)(bnQ + HID);                       // NN+1
  int* curs  = offs + NN + 1;                           // NN
  int* perm  = curs + NN;                               // NE

  const int* esrc = ei;
  const int* edst = ei + NE;

  kConvW  <<<(6*16384 + 48*128 + 255)/256, 256, 0, stream>>>(w1, w2, wtb, zb);
  kZero   <<<(NN + 255)/256, 256, 0, stream>>>(curs, NN);
  kHist   <<<(NE + 255)/256, 256, 0, stream>>>(edst, curs);
  kScan   <<<1, 1024, 0, stream>>>(curs, offs);
  kScatter<<<(NE + 255)/256, 256, 0, stream>>>(edst, curs, perm);
  kNodeInit<<<(NN*HID + 255)/256, 256, 0, stream>>>(x, nw, nb, h, hbf);

  for (int l = 0; l < NL; ++l){
    kAgg<<<NN, 128, 0, stream>>>(h, hbf, eattr, esrc, perm, offs,
                                 ew + (size_t)l*EIN*HID, eb + (size_t)l*HID, eps, l,
                                 zb, bnS, bnQ);
    kMlp<<<(NN + BM - 1)/BM, 256, 0, stream>>>(zb, z2,
                                 wtb + (size_t)l*16384, bb1 + (size_t)l*HID,
                                 wtb + (size_t)(3+l)*16384, bb2 + (size_t)l*HID,
                                 bnS, bnQ);
    kBn<<<(NN*HID + 255)/256, 256, 0, stream>>>(z2, bnS, bnQ,
                                 gam + (size_t)l*HID, bet + (size_t)l*HID, h, hbf);
  }

  kPool<<<NG, 192, 0, stream>>>(h, bids, tgt, temb, g);
  kHead<<<NG, 128, 0, stream>>>(g, h1w, h1b, h2w, h2b, h3w, h3b, out);
}

// Round 4
// 650.837 us; speedup vs baseline: 1.5586x; 1.3647x over previous
//
#include <hip/hip_runtime.h>

#define NN 50000
#define NE 800000
#define NIN 32
#define EIN 16
#define HID 128
#define NL 3
#define NG 256
#define TE 64
#define BM 64   // kMlp row tile
#define SCAN_B 196  // ceil(NN/256)

typedef unsigned short ushort_t;
typedef __attribute__((ext_vector_type(8))) short short8;
typedef __attribute__((ext_vector_type(4))) float f32x4;
typedef __attribute__((ext_vector_type(2))) __fp16 h2;

__device__ __forceinline__ ushort_t f2bf(float x){
  unsigned u = __float_as_uint(x);
  unsigned r = (u + 0x7fffu + ((u >> 16) & 1u)) >> 16;
  return (ushort_t)r;
}
__device__ __forceinline__ float bf2f(ushort_t v){
  return __uint_as_float(((unsigned)v) << 16);
}
__device__ __forceinline__ unsigned pkf16(float a, float b){
  h2 h = __builtin_amdgcn_cvt_pkrtz(a, b);
  union{ h2 h; unsigned u; } c; c.h = h; return c.u;
}
__device__ __forceinline__ h2 u2h(unsigned u){
  union{ unsigned u; h2 h; } c; c.u = u; return c.h;
}

typedef const __attribute__((address_space(1))) unsigned gas_t;
typedef __attribute__((address_space(3))) unsigned las_t;
__device__ __forceinline__ void stage16(const void* g, void* l){
  __builtin_amdgcn_global_load_lds((gas_t*)g, (las_t*)l, 16, 0, 0);
}

// ======================= CSR build (dst-sorted) =======================
__global__ void kZero(int* __restrict__ p, int n){
  int i = blockIdx.x*256 + threadIdx.x;
  if (i < n) p[i] = 0;
}

__global__ void kHist(const int* __restrict__ dst, int* __restrict__ cnt){
  int e = blockIdx.x*256 + threadIdx.x;
  if (e < NE) atomicAdd(&cnt[dst[e]], 1);
}

__global__ void kPartSum(const int* __restrict__ cnt, int* __restrict__ psum){
  __shared__ int sm[256];
  int b = blockIdx.x, t = threadIdx.x, i = b*256 + t;
  sm[t] = (i < NN) ? cnt[i] : 0;
  __syncthreads();
  for (int o = 128; o > 0; o >>= 1){
    if (t < o) sm[t] += sm[t + o];
    __syncthreads();
  }
  if (t == 0) psum[b] = sm[0];
}

__global__ __launch_bounds__(256) void kScanPart(const int* __restrict__ psum,
                                                 int* __restrict__ pofs, int* __restrict__ offs){
  __shared__ int sm[256];
  int t = threadIdx.x;
  int v = (t < SCAN_B) ? psum[t] : 0;
  sm[t] = v;
  __syncthreads();
  for (int o = 1; o < 256; o <<= 1){
    int x = (t >= o) ? sm[t - o] : 0;
    __syncthreads();
    sm[t] += x;
    __syncthreads();
  }
  if (t < SCAN_B) pofs[t] = sm[t] - v;
  if (t == 255) offs[NN] = sm[255];
}

__global__ void kScanApply(const int* __restrict__ cnt, const int* __restrict__ pofs,
                           int* __restrict__ offs, int* __restrict__ curs){
  __shared__ int sm[256];
  int b = blockIdx.x, t = threadIdx.x, i = b*256 + t;
  int v = (i < NN) ? cnt[i] : 0;
  sm[t] = v;
  __syncthreads();
  for (int o = 1; o < 256; o <<= 1){
    int x = (t >= o) ? sm[t - o] : 0;
    __syncthreads();
    sm[t] += x;
    __syncthreads();
  }
  int ex = sm[t] - v + pofs[b];
  if (i < NN){ offs[i] = ex; curs[i] = ex; }
}

__global__ void kScatter(const int* __restrict__ dst, const int* __restrict__ src,
                         int* __restrict__ curs, int* __restrict__ perm, int* __restrict__ srcPos){
  int e = blockIdx.x*256 + threadIdx.x;
  if (e < NE){
    int p = atomicAdd(&curs[dst[e]], 1);
    perm[p] = e;
    srcPos[p] = src[e];
  }
}

// eattr rows permuted to CSR order, packed f16 pairs: eaPos[p*8 + w] = half2(ea[2w], ea[2w+1])
__global__ void kPermEA(const float* __restrict__ eattr, const int* __restrict__ perm,
                        unsigned* __restrict__ eaPos){
  int gid = blockIdx.x*256 + threadIdx.x;   // NE*2
  if (gid >= NE*2) return;
  int p = gid >> 1, part = gid & 1;
  int e = perm[p];
  const float* row = eattr + (size_t)e*EIN + part*8;
  float4 v0 = *(const float4*)row;
  float4 v1 = *(const float4*)(row + 4);
  uint4 d;
  d.x = pkf16(v0.x, v0.y); d.y = pkf16(v0.z, v0.w);
  d.z = pkf16(v1.x, v1.y); d.w = pkf16(v1.z, v1.w);
  *(uint4*)&eaPos[(size_t)p*8 + part*4] = d;
}

// ======================= W -> bf16, transposed + pre-swizzled; zero zb tail =======================
__global__ void kConvW(const float* __restrict__ w1, const float* __restrict__ w2,
                       ushort_t* __restrict__ wtb, ushort_t* __restrict__ zb){
  int gid = blockIdx.x*256 + threadIdx.x;
  if (gid < 6*16384){
    int mat = gid >> 14, idx = gid & 16383;
    int k = idx >> 7, n = idx & 127;
    const float* src = (mat < 3) ? (w1 + (size_t)mat*16384) : (w2 + (size_t)(mat-3)*16384);
    wtb[(size_t)mat*16384 + n*128 + (k ^ ((n&7)<<3))] = f2bf(src[idx]);
  } else {
    int t = gid - 6*16384;
    if (t < 48*128) zb[(size_t)NN*HID + t] = 0;
  }
}

// ======================= node embed -> hbf =======================
__global__ void kNodeInit(const float* __restrict__ x, const float* __restrict__ w,
                          const float* __restrict__ b, ushort_t* __restrict__ hbf){
  int gid = blockIdx.x*256 + threadIdx.x;   // NN*64
  if (gid >= NN*64) return;
  int n = gid >> 6, c = (gid & 63)*2;
  const float* xr = x + (size_t)n*NIN;
  float a0 = b[c], a1 = b[c+1];
  #pragma unroll
  for (int k = 0; k < NIN; ++k){
    float xv = xr[k];
    a0 = fmaf(xv, w[k*HID + c],     a0);
    a1 = fmaf(xv, w[k*HID + c + 1], a1);
  }
  unsigned ow = (unsigned)f2bf(a0) | ((unsigned)f2bf(a1) << 16);
  *(unsigned*)&hbf[(size_t)n*HID + c] = ow;
}

// ======================= GINE aggregate: wave-per-node, packed-f16 edge-Lin =======================
__device__ __forceinline__ void edgeBody(int s, uint4 e0, uint4 e1,
    const h2* wA, const h2* wB, const ushort_t* __restrict__ hbf, int c0,
    float b0, float b1, float& acc0, float& acc1){
  unsigned hs = *(const unsigned*)&hbf[(size_t)s*HID + c0];
  h2 za; za[0] = (__fp16)0.f; za[1] = (__fp16)0.f;
  h2 accA = za, accB = za;
  accA = __builtin_elementwise_fma(u2h(e0.x), wA[0], accA);
  accB = __builtin_elementwise_fma(u2h(e0.x), wB[0], accB);
  accA = __builtin_elementwise_fma(u2h(e0.y), wA[1], accA);
  accB = __builtin_elementwise_fma(u2h(e0.y), wB[1], accB);
  accA = __builtin_elementwise_fma(u2h(e0.z), wA[2], accA);
  accB = __builtin_elementwise_fma(u2h(e0.z), wB[2], accB);
  accA = __builtin_elementwise_fma(u2h(e0.w), wA[3], accA);
  accB = __builtin_elementwise_fma(u2h(e0.w), wB[3], accB);
  accA = __builtin_elementwise_fma(u2h(e1.x), wA[4], accA);
  accB = __builtin_elementwise_fma(u2h(e1.x), wB[4], accB);
  accA = __builtin_elementwise_fma(u2h(e1.y), wA[5], accA);
  accB = __builtin_elementwise_fma(u2h(e1.y), wB[5], accB);
  accA = __builtin_elementwise_fma(u2h(e1.z), wA[6], accA);
  accB = __builtin_elementwise_fma(u2h(e1.z), wB[6], accB);
  accA = __builtin_elementwise_fma(u2h(e1.w), wA[7], accA);
  accB = __builtin_elementwise_fma(u2h(e1.w), wB[7], accB);
  float ev0 = (float)accA[0] + (float)accA[1] + b0;
  float ev1 = (float)accB[0] + (float)accB[1] + b1;
  float h0v = bf2f((ushort_t)(hs & 0xffffu));
  float h1v = bf2f((ushort_t)(hs >> 16));
  acc0 += fmaxf(h0v + ev0, 0.f);
  acc1 += fmaxf(h1v + ev1, 0.f);
}

__global__ __launch_bounds__(256) void kAgg(
    const ushort_t* __restrict__ hbf, const unsigned* __restrict__ eaPos,
    const int* __restrict__ srcPos, const int* __restrict__ offs,
    const float* __restrict__ Wl, const float* __restrict__ bl,
    const float* __restrict__ epsArr, int layer,
    ushort_t* __restrict__ zb, float* __restrict__ bnS, float* __restrict__ bnQ){
  __shared__ unsigned easu[4][16][8];   // [wave][edge][8 packed f16 pairs]
  __shared__ int srcsS[4][16];
  int tid = threadIdx.x, lane = tid & 63, wv = tid >> 6;
  if (blockIdx.x == 0 && tid < 128){ bnS[tid] = 0.f; bnQ[tid] = 0.f; }
  int c0 = 2*lane;
  // W columns for channels c0,c0+1 as packed f16 k-pairs
  h2 wA[8], wB[8];
  #pragma unroll
  for (int kk = 0; kk < 8; ++kk){
    wA[kk] = __builtin_amdgcn_cvt_pkrtz(Wl[(2*kk)*HID + c0],     Wl[(2*kk+1)*HID + c0]);
    wB[kk] = __builtin_amdgcn_cvt_pkrtz(Wl[(2*kk)*HID + c0 + 1], Wl[(2*kk+1)*HID + c0 + 1]);
  }
  float b0 = bl[c0], b1 = bl[c0+1];
  float ep1 = 1.f + epsArr[layer];
  int gw = blockIdx.x*4 + wv, nwv = gridDim.x*4;
  for (int n = gw; n < NN; n += nwv){
    int s0 = offs[n], s1 = offs[n+1];
    float acc0 = 0.f, acc1 = 0.f;
    for (int j = s0; j < s1; j += 16){
      int cnt = min(16, s1 - j);
      if (lane < cnt) srcsS[wv][lane] = srcPos[j + lane];
      if (lane < 4*cnt){
        int r = lane >> 2, part = lane & 3;
        *(uint2*)&easu[wv][r][part*2] = *(const uint2*)&eaPos[(size_t)(j + r)*8 + part*2];
      }
      asm volatile("s_waitcnt lgkmcnt(0)" ::: "memory");
      if (cnt == 16){
        #pragma unroll 8
        for (int i = 0; i < 16; ++i){
          int s = srcsS[wv][i];
          const uint4* eap = (const uint4*)&easu[wv][i][0];
          edgeBody(s, eap[0], eap[1], wA, wB, hbf, c0, b0, b1, acc0, acc1);
        }
      } else {
        for (int i = 0; i < cnt; ++i){
          int s = srcsS[wv][i];
          const uint4* eap = (const uint4*)&easu[wv][i][0];
          edgeBody(s, eap[0], eap[1], wA, wB, hbf, c0, b0, b1, acc0, acc1);
        }
      }
      asm volatile("s_waitcnt lgkmcnt(0)" ::: "memory");  // eas reads done before next batch overwrites
    }
    unsigned hw = *(const unsigned*)&hbf[(size_t)n*HID + c0];
    float z0v = ep1 * bf2f((ushort_t)(hw & 0xffffu)) + acc0;
    float z1v = ep1 * bf2f((ushort_t)(hw >> 16)) + acc1;
    unsigned ow = (unsigned)f2bf(z0v) | ((unsigned)f2bf(z1v) << 16);
    *(unsigned*)&zb[(size_t)n*HID + (c0 ^ ((n & 7) << 3))] = ow;
  }
}

// ======================= fused MLP via MFMA =======================
__global__ __launch_bounds__(256, 1) void kMlp(
    const ushort_t* __restrict__ zb, float* __restrict__ z2,
    const ushort_t* __restrict__ w1t, const float* __restrict__ b1,
    const ushort_t* __restrict__ w2t, const float* __restrict__ b2,
    float* __restrict__ bnS, float* __restrict__ bnQ){
  __shared__ __align__(16) ushort_t As[BM*128];
  __shared__ __align__(16) ushort_t Bs[128*128];
  __shared__ float red[256];
  int tid  = threadIdx.x;
  int lane = tid & 63;
  int w    = tid >> 6;
  int ln   = tid & 15;
  int q    = (tid >> 4) & 3;
  int rbase = blockIdx.x * BM;
  int m0 = (w >> 1) * 32;
  int wc = (w & 1) * 64;

  const char* gA = (const char*)(zb + (size_t)rbase * HID);
  #pragma unroll
  for (int it = 0; it < 4; ++it)
    stage16(gA + (w*4096 + it*1024 + lane*16), (char*)As + (w*4096 + it*1024));
  const char* gB1 = (const char*)w1t;
  #pragma unroll
  for (int it = 0; it < 8; ++it)
    stage16(gB1 + (w*8192 + it*1024 + lane*16), (char*)Bs + (w*8192 + it*1024));
  __syncthreads();

  f32x4 acc[2][4];
  #pragma unroll
  for (int i = 0; i < 2; ++i)
    #pragma unroll
    for (int j = 0; j < 4; ++j) acc[i][j] = (f32x4)0.f;

  #pragma unroll
  for (int kk = 0; kk < 4; ++kk){
    int kb = kk*32 + q*8;
    short8 af[2], bf[4];
    #pragma unroll
    for (int i = 0; i < 2; ++i){
      int m = m0 + 16*i + ln;
      af[i] = *(const short8*)&As[m*128 + (kb ^ ((m&7)<<3))];
    }
    #pragma unroll
    for (int j = 0; j < 4; ++j){
      int nn = wc + 16*j + ln;
      bf[j] = *(const short8*)&Bs[nn*128 + (kb ^ ((nn&7)<<3))];
    }
    #pragma unroll
    for (int i = 0; i < 2; ++i)
      #pragma unroll
      for (int j = 0; j < 4; ++j)
        acc[i][j] = __builtin_amdgcn_mfma_f32_16x16x32_bf16(af[i], bf[j], acc[i][j], 0, 0, 0);
  }
  __syncthreads();

  const char* gB2 = (const char*)w2t;
  #pragma unroll
  for (int it = 0; it < 8; ++it)
    stage16(gB2 + (w*8192 + it*1024 + lane*16), (char*)Bs + (w*8192 + it*1024));
  {
    float b1v[4];
    #pragma unroll
    for (int j = 0; j < 4; ++j) b1v[j] = b1[wc + 16*j + ln];
    #pragma unroll
    for (int i = 0; i < 2; ++i){
      #pragma unroll
      for (int j = 0; j < 4; ++j){
        int kc = wc + 16*j + ln;
        #pragma unroll
        for (int r = 0; r < 4; ++r){
          int m = m0 + 16*i + 4*q + r;
          As[m*128 + (kc ^ ((m&7)<<3))] = f2bf(fmaxf(acc[i][j][r] + b1v[j], 0.f));
        }
      }
    }
  }
  #pragma unroll
  for (int i = 0; i < 2; ++i)
    #pragma unroll
    for (int j = 0; j < 4; ++j) acc[i][j] = (f32x4)0.f;
  __syncthreads();

  #pragma unroll
  for (int kk = 0; kk < 4; ++kk){
    int kb = kk*32 + q*8;
    short8 af[2], bf[4];
    #pragma unroll
    for (int i = 0; i < 2; ++i){
      int m = m0 + 16*i + ln;
      af[i] = *(const short8*)&As[m*128 + (kb ^ ((m&7)<<3))];
    }
    #pragma unroll
    for (int j = 0; j < 4; ++j){
      int nn = wc + 16*j + ln;
      bf[j] = *(const short8*)&Bs[nn*128 + (kb ^ ((nn&7)<<3))];
    }
    #pragma unroll
    for (int i = 0; i < 2; ++i)
      #pragma unroll
      for (int j = 0; j < 4; ++j)
        acc[i][j] = __builtin_amdgcn_mfma_f32_16x16x32_bf16(af[i], bf[j], acc[i][j], 0, 0, 0);
  }

  float b2v[4];
  #pragma unroll
  for (int j = 0; j < 4; ++j) b2v[j] = b2[wc + 16*j + ln];
  float ps[4], pq[4];
  #pragma unroll
  for (int j = 0; j < 4; ++j){ ps[j] = 0.f; pq[j] = 0.f; }
  #pragma unroll
  for (int i = 0; i < 2; ++i){
    #pragma unroll
    for (int r = 0; r < 4; ++r){
      int rg = rbase + m0 + 16*i + 4*q + r;
      if (rg < NN){
        #pragma unroll
        for (int j = 0; j < 4; ++j){
          float v = acc[i][j][r] + b2v[j];
          z2[(size_t)rg*HID + wc + 16*j + ln] = v;
          ps[j] += v; pq[j] += v*v;
        }
      }
    }
  }
  red[tid] = 0.f;
  if (tid < 128) red[128 + tid] = 0.f;
  __syncthreads();
  #pragma unroll
  for (int j = 0; j < 4; ++j){
    int c = wc + 16*j + ln;
    atomicAdd(&red[c], ps[j]);
    atomicAdd(&red[128 + c], pq[j]);
  }
  __syncthreads();
  if (tid < 128){
    atomicAdd(&bnS[tid], red[tid]);
    atomicAdd(&bnQ[tid], red[128 + tid]);
  }
}

// ======================= BN apply + ReLU -> hbf =======================
__global__ void kBn(const float* __restrict__ z2, const float* __restrict__ bnS,
                    const float* __restrict__ bnQ, const float* __restrict__ gamma,
                    const float* __restrict__ beta, ushort_t* __restrict__ hbf){
  int gid = blockIdx.x*256 + threadIdx.x;   // NN*64
  if (gid >= NN*64) return;
  int r = gid >> 6, c = (gid & 63)*2;
  float2 zv = *(const float2*)&z2[(size_t)r*HID + c];
  float2 sS = *(const float2*)&bnS[c];
  float2 sQ = *(const float2*)&bnQ[c];
  float2 gm = *(const float2*)&gamma[c];
  float2 bt = *(const float2*)&beta[c];
  float m0 = sS.x*(1.f/NN), m1 = sS.y*(1.f/NN);
  float v0 = sQ.x*(1.f/NN) - m0*m0, v1 = sQ.y*(1.f/NN) - m1*m1;
  float o0 = fmaxf((zv.x - m0)*rsqrtf(v0 + 1e-5f)*gm.x + bt.x, 0.f);
  float o1 = fmaxf((zv.y - m1)*rsqrtf(v1 + 1e-5f)*gm.y + bt.y, 0.f);
  unsigned ow = (unsigned)f2bf(o0) | ((unsigned)f2bf(o1) << 16);
  *(unsigned*)&hbf[(size_t)r*HID + c] = ow;
}

// ======================= pool =======================
__global__ __launch_bounds__(192) void kPool(const ushort_t* __restrict__ hbf, const int* __restrict__ bid,
                      const int* __restrict__ tidx, const float* __restrict__ temb,
                      float* __restrict__ g){
  int b = blockIdx.x, t = threadIdx.x;
  int lo = 0, hi = NN;
  while (lo < hi){ int m = (lo + hi) >> 1; if (bid[m] < b) lo = m + 1; else hi = m; }
  int s = lo;
  lo = 0; hi = NN;
  while (lo < hi){ int m = (lo + hi) >> 1; if (bid[m] < b + 1) lo = m + 1; else hi = m; }
  int e = lo;
  if (t < HID){
    float acc = 0.f;
    for (int n = s; n < e; ++n) acc += bf2f(hbf[(size_t)n*HID + t]);
    g[b*192 + t] = acc;
  } else {
    int j = t - HID;
    g[b*192 + HID + j] = temb[tidx[b]*TE + j];
  }
}

// ======================= head MLP =======================
__global__ __launch_bounds__(128) void kHead(const float* __restrict__ g,
    const float* __restrict__ w1, const float* __restrict__ b1,
    const float* __restrict__ w2, const float* __restrict__ b2,
    const float* __restrict__ w3, const float* __restrict__ b3,
    float* __restrict__ out){
  __shared__ float gv[192];
  __shared__ float t1[128];
  __shared__ float t2[64];
  int b = blockIdx.x, t = threadIdx.x;
  gv[t] = g[b*192 + t];
  if (t < 64) gv[128 + t] = g[b*192 + 128 + t];
  __syncthreads();
  float acc = b1[t];
  for (int k = 0; k < 192; ++k) acc = fmaf(gv[k], w1[k*HID + t], acc);
  t1[t] = fmaxf(acc, 0.f);
  __syncthreads();
  if (t < 64){
    float a2 = b2[t];
    for (int k = 0; k < 128; ++k) a2 = fmaf(t1[k], w2[k*64 + t], a2);
    t2[t] = fmaxf(a2, 0.f);
  }
  __syncthreads();
  if (t == 0){
    float s = b3[0];
    for (int k = 0; k < 64; ++k) s = fmaf(t2[k], w3[k], s);
    out[b] = s;
  }
}

// ======================= launch =======================
extern "C" void kernel_launch(void* const* d_in, const int* in_sizes, int n_in,
                              void* d_out, int out_size, void* d_ws, size_t ws_size,
                              hipStream_t stream){
  const float* x     = (const float*)d_in[0];
  const int*   ei    = (const int*)  d_in[1];
  const float* eattr = (const float*)d_in[2];
  const int*   bids  = (const int*)  d_in[3];
  const int*   tgt   = (const int*)  d_in[4];
  const float* nw    = (const float*)d_in[5];
  const float* nb    = (const float*)d_in[6];
  const float* eps   = (const float*)d_in[7];
  const float* ew    = (const float*)d_in[8];
  const float* eb    = (const float*)d_in[9];
  const float* w1    = (const float*)d_in[10];
  const float* bb1   = (const float*)d_in[11];
  const float* w2    = (const float*)d_in[12];
  const float* bb2   = (const float*)d_in[13];
  const float* gam   = (const float*)d_in[14];
  const float* bet   = (const float*)d_in[15];
  const float* temb  = (const float*)d_in[16];
  const float* h1w   = (const float*)d_in[17];
  const float* h1b   = (const float*)d_in[18];
  const float* h2w   = (const float*)d_in[19];
  const float* h2b   = (const float*)d_in[20];
  const float* h3w   = (const float*)d_in[21];
  const float* h3b   = (const float*)d_in[22];
  float* out = (float*)d_out;

  ushort_t* zb  = (ushort_t*)d_ws;                      // (NN+48)*128
  ushort_t* wtb = zb + (size_t)(NN + 48)*HID;           // 6*16384
  ushort_t* hbf = wtb + (size_t)6*16384;                // NN*128
  unsigned* eaPos = (unsigned*)(hbf + (size_t)NN*HID);  // NE*8
  float* z2  = (float*)(eaPos + (size_t)NE*8);          // NN*128
  float* g   = z2 + (size_t)NN*HID;                     // NG*192
  float* bnS = g  + (size_t)NG*192;                     // 128
  float* bnQ = bnS + HID;                               // 128
  int* offs  = (int*)(bnQ + HID);                       // NN+1
  int* cnt   = offs + NN + 1;                           // NN
  int* curs  = cnt + NN;                                // NN
  int* perm  = curs + NN;                               // NE
  int* srcPos= perm + NE;                               // NE
  int* psum  = srcPos + NE;                             // 256
  int* pofs  = psum + 256;                              // 256

  const int* esrc = ei;
  const int* edst = ei + NE;

  kConvW   <<<(6*16384 + 48*128 + 255)/256, 256, 0, stream>>>(w1, w2, wtb, zb);
  kZero    <<<(NN + 255)/256, 256, 0, stream>>>(cnt, NN);
  kHist    <<<(NE + 255)/256, 256, 0, stream>>>(edst, cnt);
  kPartSum <<<SCAN_B, 256, 0, stream>>>(cnt, psum);
  kScanPart<<<1, 256, 0, stream>>>(psum, pofs, offs);
  kScanApply<<<SCAN_B, 256, 0, stream>>>(cnt, pofs, offs, curs);
  kScatter <<<(NE + 255)/256, 256, 0, stream>>>(edst, esrc, curs, perm, srcPos);
  kPermEA  <<<(NE*2 + 255)/256, 256, 0, stream>>>(eattr, perm, eaPos);
  kNodeInit<<<(NN*64 + 255)/256, 256, 0, stream>>>(x, nw, nb, hbf);

  for (int l = 0; l < NL; ++l){
    kAgg<<<2048, 256, 0, stream>>>(hbf, eaPos, srcPos, offs,
                                 ew + (size_t)l*EIN*HID, eb + (size_t)l*HID, eps, l,
                                 zb, bnS, bnQ);
    kMlp<<<(NN + BM - 1)/BM, 256, 0, stream>>>(zb, z2,
                                 wtb + (size_t)l*16384, bb1 + (size_t)l*HID,
                                 wtb + (size_t)(3+l)*16384, bb2 + (size_t)l*HID,
                                 bnS, bnQ);
    kBn<<<(NN*64 + 255)/256, 256, 0, stream>>>(z2, bnS, bnQ,
                                 gam + (size_t)l*HID, bet + (size_t)l*HID, hbf);
  }

  kPool<<<NG, 192, 0, stream>>>(hbf, bids, tgt, temb, g);
  kHead<<<NG, 128, 0, stream>>>(g, h1w, h1b, h2w, h2b, h3w, h3b, out);
}